// Round 8
// baseline (184.384 us; speedup 1.0000x reference)
//
#include <hip/hip_runtime.h>
#include <math.h>

// Problem constants
constexpr int Bb = 256;
constexpr int Ll = 512;
constexpr int Dd = 768;
constexpr int Pp = 30;
constexpr int Kk = 4;
constexpr int LOUT = Kk + Ll;          // 516
constexpr int D4   = Dd / 4;           // 192 float4 per row
constexpr int CHUNKS = 8;              // grid = 8*256 = 2048 blocks = 8/CU exactly
constexpr int ROWS   = Ll / CHUNKS;    // 64 rows per chunk
constexpr int TPB    = 256;            // 4 waves; 8 blocks/CU = 32 waves/CU

typedef float f32x4 __attribute__((ext_vector_type(4)));

// d_out layout (float elements): prompted_embedding, similarity, reduce_sim, idx(as float)
constexpr size_t SIM_OFF = (size_t)Bb * LOUT * Dd;        // 101,449,728
constexpr size_t RS_OFF  = SIM_OFF + (size_t)Bb * Pp;     // +7680
constexpr size_t IDX_OFF = RS_OFF + 1;                    // +1

// d_ws layout (float elements)
constexpr size_t PART_OFF = 0;                            // Bb*CHUNKS*Dd floats (6.3 MB)
constexpr size_t RED_OFF  = (size_t)Bb * CHUNKS * Dd;     // Bb floats

// ---------------------------------------------------------------------------
// Kernel A: copy x_embed chunk -> out rows [K..K+L) while accumulating column
// sums. NT loads (zero reuse, don't pollute L2) + PLAIN stores (L2 write-back
// acts as an elastic buffer decoupling wave progress from HBM write latency —
// the harness fill kernels sustain 6.9 TB/s with plain stores vs our 5.1 with
// NT). Transposed LDS cls[wave][col] combine is conflict-free.
__global__ __launch_bounds__(TPB, 8)
void copy_mean_kernel(const f32x4* __restrict__ x,
                      f32x4* __restrict__ out,
                      f32x4* __restrict__ part) {
    __shared__ f32x4 cls[4][D4];         // 12 KB, transposed: [wave][col]

    const int c = blockIdx.x;            // chunk
    const int b = blockIdx.y;            // batch
    const int t = threadIdx.x;           // 0..255
    const int m = t >> 6;                // wave id 0..3

    const f32x4* src = x   + (size_t)(b * Ll + c * ROWS) * D4 + t;
    f32x4*       dst = out + (size_t)(b * LOUT + Kk + c * ROWS) * D4 + t;

    f32x4 a0 = {0,0,0,0}, a1 = {0,0,0,0}, a2 = {0,0,0,0};
    // 8 iterations x 1536 f32x4 (8 rows) per block; 6 NT loads then 6 plain stores.
    for (int it = 0; it < 8; ++it) {
        const size_t o = (size_t)it * 1536;
        f32x4 v0 = __builtin_nontemporal_load(src + o);
        f32x4 v1 = __builtin_nontemporal_load(src + o + 256);
        f32x4 v2 = __builtin_nontemporal_load(src + o + 512);
        f32x4 v3 = __builtin_nontemporal_load(src + o + 768);
        f32x4 v4 = __builtin_nontemporal_load(src + o + 1024);
        f32x4 v5 = __builtin_nontemporal_load(src + o + 1280);
        dst[o]        = v0;
        dst[o + 256]  = v1;
        dst[o + 512]  = v2;
        dst[o + 768]  = v3;
        dst[o + 1024] = v4;
        dst[o + 1280] = v5;
        a0 += v0 + v3;                   // col class (t) % 192
        a1 += v1 + v4;                   // col class (t+64) % 192
        a2 += v2 + v5;                   // col class (t+128) % 192
    }
    // Each wave's 64 threads x 3 classes cover all 192 cols exactly once.
    cls[m][t % D4]         = a0;
    cls[m][(t + 64) % D4]  = a1;
    cls[m][(t + 128) % D4] = a2;
    __syncthreads();

    if (t < D4) {
        const f32x4 s = cls[0][t] + cls[1][t] + cls[2][t] + cls[3][t];
        part[(size_t)(b * CHUNKS + c) * D4 + t] = s;   // plain cached store
    }
}

// ---------------------------------------------------------------------------
// Kernel C: per-batch tail. 256 blocks x 256.
__global__ void sim_topk_kernel(const float* __restrict__ part,
                                const float* __restrict__ prompt,
                                float* __restrict__ out,
                                float* __restrict__ red) {
    __shared__ float  xn[Dd];
    __shared__ float  sims[Pp];
    __shared__ int    tidx[Kk];
    __shared__ double smem[4];

    const int b = blockIdx.x;
    const int t = threadIdx.x;

    // combine chunk partials (double), mean, sum of squares: t<192, 4 floats
    double md[4];
    double ssl = 0.0;
    if (t < D4) {
#pragma unroll
        for (int k = 0; k < 4; ++k) {
            double s = 0.0;
#pragma unroll
            for (int cc = 0; cc < CHUNKS; ++cc)
                s += (double)part[(size_t)(b * CHUNKS + cc) * Dd + 4 * t + k];
            md[k] = s * (1.0 / Ll);
            ssl += md[k] * md[k];
        }
    }
    for (int off = 32; off > 0; off >>= 1) ssl += __shfl_down(ssl, off, 64);
    if ((t & 63) == 0) smem[t >> 6] = ssl;
    __syncthreads();
    const double rs = 1.0 / sqrt(fmax(smem[0] + smem[1] + smem[2] + smem[3], 1e-12));
    if (t < D4) {
#pragma unroll
        for (int k = 0; k < 4; ++k)
            xn[4 * t + k] = (float)(md[k] * rs);
    }
    __syncthreads();

    // similarity with fused prompt normalization: 8 lanes per prompt
    if (t < Pp * 8) {
        const int p = t >> 3;
        const int g = t & 7;
        double dot = 0.0, pss = 0.0;
        for (int i = g; i < Dd; i += 8) {
            const double pv = (double)prompt[p * Dd + i];
            dot += (double)xn[i] * pv;
            pss += pv * pv;
        }
#pragma unroll
        for (int off = 4; off > 0; off >>= 1) {
            dot += __shfl_down(dot, off, 8);
            pss += __shfl_down(pss, off, 8);
        }
        if (g == 0) {
            const float sv = (float)(dot / sqrt(fmax(pss, 1e-12)));
            sims[p] = sv;
            out[SIM_OFF + (size_t)b * Pp + p] = sv;
        }
    }
    __syncthreads();

    // top-4 (strict > keeps earliest index on ties, matching lax.top_k)
    if (t == 0) {
        float sv[Pp];
        for (int p = 0; p < Pp; ++p) sv[p] = sims[p];
        double rsum = 0.0;
        for (int k = 0; k < Kk; ++k) {
            float best = -INFINITY;
            int   bi   = 0;
            for (int p = 0; p < Pp; ++p)
                if (sv[p] > best) { best = sv[p]; bi = p; }
            tidx[k] = bi;
            out[IDX_OFF + (size_t)b * Kk + k] = (float)bi;
            rsum += (double)best;
            sv[bi] = -INFINITY;
        }
        red[b] = (float)rsum;
    }
    __syncthreads();

    // batched_prompt: out[b, k, :] = prompt[tidx[k], :]  (768 f32x4 = 256*3)
    {
        const f32x4* pr4 = (const f32x4*)prompt;
        f32x4*       o4  = (f32x4*)out;
#pragma unroll
        for (int jj = 0; jj < 3; ++jj) {
            const int j   = t + 256 * jj;
            const int k   = j / D4;
            const int col = j % D4;
            o4[(size_t)(b * LOUT + k) * D4 + col] = pr4[(size_t)tidx[k] * D4 + col];
        }
    }
}

// ---------------------------------------------------------------------------
// Kernel D: reduce_sim = sum_b red[b] / B. 1 block x 256.
__global__ void finalize_kernel(const float* __restrict__ red,
                                float* __restrict__ out) {
    __shared__ double smem[4];
    const int t = threadIdx.x;
    double v = (double)red[t];
    for (int off = 32; off > 0; off >>= 1) v += __shfl_down(v, off, 64);
    if ((t & 63) == 0) smem[t >> 6] = v;
    __syncthreads();
    if (t == 0)
        out[RS_OFF] = (float)((smem[0] + smem[1] + smem[2] + smem[3]) * (1.0 / Bb));
}

// ---------------------------------------------------------------------------
extern "C" void kernel_launch(void* const* d_in, const int* in_sizes, int n_in,
                              void* d_out, int out_size, void* d_ws, size_t ws_size,
                              hipStream_t stream) {
    const float* x_embed = (const float*)d_in[0];   // [256,512,768]
    const float* prompt  = (const float*)d_in[1];   // [30,768]
    float* out = (float*)d_out;
    float* ws  = (float*)d_ws;

    float* part = ws + PART_OFF;
    float* red  = ws + RED_OFF;

    copy_mean_kernel<<<dim3(CHUNKS, Bb), TPB, 0, stream>>>(
        (const f32x4*)x_embed, (f32x4*)out, (f32x4*)part);

    sim_topk_kernel<<<Bb, TPB, 0, stream>>>(part, prompt, out, red);

    finalize_kernel<<<1, Bb, 0, stream>>>(red, out);
}

// Round 9
// 171.367 us; speedup vs baseline: 1.0760x; 1.0760x over previous
//
#include <hip/hip_runtime.h>
#include <math.h>

// Problem constants
constexpr int Bb = 256;
constexpr int Ll = 512;
constexpr int Dd = 768;
constexpr int Pp = 30;
constexpr int Kk = 4;
constexpr int LOUT = Kk + Ll;          // 516
constexpr int D4   = Dd / 4;           // 192 float4 per row
constexpr int CHUNKS = 8;              // grid = 8*256 = 2048 blocks
constexpr int ROWS   = Ll / CHUNKS;    // 64 rows per chunk (192 KB per block)
constexpr int TPB    = 256;

typedef float f32x4 __attribute__((ext_vector_type(4)));

// d_out layout (float elements): prompted_embedding, similarity, reduce_sim, idx(as float)
constexpr size_t SIM_OFF = (size_t)Bb * LOUT * Dd;        // 101,449,728
constexpr size_t RS_OFF  = SIM_OFF + (size_t)Bb * Pp;     // +7680
constexpr size_t IDX_OFF = RS_OFF + 1;                    // +1

// d_ws layout (float elements)
constexpr size_t PART_OFF = 0;                            // Bb*CHUNKS*Dd floats (6.3 MB)
constexpr size_t RED_OFF  = (size_t)Bb * CHUNKS * Dd;     // Bb floats

// ---------------------------------------------------------------------------
// Kernel A: copy + column sums, deep-MLP variant. __launch_bounds__(256,4)
// lifts VGPR cap to 128 -> 16 f32x4 loads in flight per thread (16 KB/wave,
// 256 KB/CU at 16 waves/CU, 1.33x R7) with long same-direction HBM bursts.
// NT on both streams (R7/R8 A/B: NT stores worth ~10 us, plain stores lose).
// Column class of element (t + 64*(p+j)) mod 192 depends only on (p+j)%3.
__global__ __launch_bounds__(TPB, 4)
void copy_mean_kernel(const f32x4* __restrict__ x,
                      f32x4* __restrict__ out,
                      f32x4* __restrict__ part) {
    __shared__ f32x4 cls[4][D4];         // 12 KB, transposed: [wave][col]

    const int c = blockIdx.x;            // chunk
    const int b = blockIdx.y;            // batch
    const int t = threadIdx.x;           // 0..255
    const int m = t >> 6;                // wave id 0..3

    const f32x4* src = x   + (size_t)(b * Ll + c * ROWS) * D4 + t;
    f32x4*       dst = out + (size_t)(b * LOUT + Kk + c * ROWS) * D4 + t;

    f32x4 acc[3];
    acc[0] = f32x4{0,0,0,0}; acc[1] = f32x4{0,0,0,0}; acc[2] = f32x4{0,0,0,0};

    // 3 outer iters x (16 NT loads, then 16 NT stores). 4096 f32x4 per iter.
#pragma unroll
    for (int p = 0; p < 3; ++p) {
        const size_t o = (size_t)p * 4096;
        f32x4 v[16];
#pragma unroll
        for (int j = 0; j < 16; ++j)
            v[j] = __builtin_nontemporal_load(src + o + j * 256);
#pragma unroll
        for (int j = 0; j < 16; ++j) {
            __builtin_nontemporal_store(v[j], dst + o + j * 256);
            acc[(p + j) % 3] += v[j];
        }
    }

    // acc[i] holds column class (t + 64*i) % 192; each wave's 64 threads x 3
    // classes cover all 192 cols exactly once -> conflict-free combine.
    cls[m][t % D4]         = acc[0];
    cls[m][(t + 64) % D4]  = acc[1];
    cls[m][(t + 128) % D4] = acc[2];
    __syncthreads();

    if (t < D4) {
        const f32x4 s = cls[0][t] + cls[1][t] + cls[2][t] + cls[3][t];
        part[(size_t)(b * CHUNKS + c) * D4 + t] = s;   // plain cached store
    }
}

// ---------------------------------------------------------------------------
// Kernel C: per-batch tail. 256 blocks x 256.
__global__ void sim_topk_kernel(const float* __restrict__ part,
                                const float* __restrict__ prompt,
                                float* __restrict__ out,
                                float* __restrict__ red) {
    __shared__ float  xn[Dd];
    __shared__ float  sims[Pp];
    __shared__ int    tidx[Kk];
    __shared__ double smem[4];

    const int b = blockIdx.x;
    const int t = threadIdx.x;

    // combine chunk partials (double), mean, sum of squares: t<192, 4 floats
    double md[4];
    double ssl = 0.0;
    if (t < D4) {
#pragma unroll
        for (int k = 0; k < 4; ++k) {
            double s = 0.0;
#pragma unroll
            for (int cc = 0; cc < CHUNKS; ++cc)
                s += (double)part[(size_t)(b * CHUNKS + cc) * Dd + 4 * t + k];
            md[k] = s * (1.0 / Ll);
            ssl += md[k] * md[k];
        }
    }
    for (int off = 32; off > 0; off >>= 1) ssl += __shfl_down(ssl, off, 64);
    if ((t & 63) == 0) smem[t >> 6] = ssl;
    __syncthreads();
    const double rs = 1.0 / sqrt(fmax(smem[0] + smem[1] + smem[2] + smem[3], 1e-12));
    if (t < D4) {
#pragma unroll
        for (int k = 0; k < 4; ++k)
            xn[4 * t + k] = (float)(md[k] * rs);
    }
    __syncthreads();

    // similarity with fused prompt normalization: 8 lanes per prompt
    if (t < Pp * 8) {
        const int p = t >> 3;
        const int g = t & 7;
        double dot = 0.0, pss = 0.0;
        for (int i = g; i < Dd; i += 8) {
            const double pv = (double)prompt[p * Dd + i];
            dot += (double)xn[i] * pv;
            pss += pv * pv;
        }
#pragma unroll
        for (int off = 4; off > 0; off >>= 1) {
            dot += __shfl_down(dot, off, 8);
            pss += __shfl_down(pss, off, 8);
        }
        if (g == 0) {
            const float sv = (float)(dot / sqrt(fmax(pss, 1e-12)));
            sims[p] = sv;
            out[SIM_OFF + (size_t)b * Pp + p] = sv;
        }
    }
    __syncthreads();

    // top-4 (strict > keeps earliest index on ties, matching lax.top_k)
    if (t == 0) {
        float sv[Pp];
        for (int p = 0; p < Pp; ++p) sv[p] = sims[p];
        double rsum = 0.0;
        for (int k = 0; k < Kk; ++k) {
            float best = -INFINITY;
            int   bi   = 0;
            for (int p = 0; p < Pp; ++p)
                if (sv[p] > best) { best = sv[p]; bi = p; }
            tidx[k] = bi;
            out[IDX_OFF + (size_t)b * Kk + k] = (float)bi;
            rsum += (double)best;
            sv[bi] = -INFINITY;
        }
        red[b] = (float)rsum;
    }
    __syncthreads();

    // batched_prompt: out[b, k, :] = prompt[tidx[k], :]  (768 f32x4 = 256*3)
    {
        const f32x4* pr4 = (const f32x4*)prompt;
        f32x4*       o4  = (f32x4*)out;
#pragma unroll
        for (int jj = 0; jj < 3; ++jj) {
            const int j   = t + 256 * jj;
            const int k   = j / D4;
            const int col = j % D4;
            o4[(size_t)(b * LOUT + k) * D4 + col] = pr4[(size_t)tidx[k] * D4 + col];
        }
    }
}

// ---------------------------------------------------------------------------
// Kernel D: reduce_sim = sum_b red[b] / B. 1 block x 256.
__global__ void finalize_kernel(const float* __restrict__ red,
                                float* __restrict__ out) {
    __shared__ double smem[4];
    const int t = threadIdx.x;
    double v = (double)red[t];
    for (int off = 32; off > 0; off >>= 1) v += __shfl_down(v, off, 64);
    if ((t & 63) == 0) smem[t >> 6] = v;
    __syncthreads();
    if (t == 0)
        out[RS_OFF] = (float)((smem[0] + smem[1] + smem[2] + smem[3]) * (1.0 / Bb));
}

// ---------------------------------------------------------------------------
extern "C" void kernel_launch(void* const* d_in, const int* in_sizes, int n_in,
                              void* d_out, int out_size, void* d_ws, size_t ws_size,
                              hipStream_t stream) {
    const float* x_embed = (const float*)d_in[0];   // [256,512,768]
    const float* prompt  = (const float*)d_in[1];   // [30,768]
    float* out = (float*)d_out;
    float* ws  = (float*)d_ws;

    float* part = ws + PART_OFF;
    float* red  = ws + RED_OFF;

    copy_mean_kernel<<<dim3(CHUNKS, Bb), TPB, 0, stream>>>(
        (const f32x4*)x_embed, (f32x4*)out, (f32x4*)part);

    sim_topk_kernel<<<Bb, TPB, 0, stream>>>(part, prompt, out, red);

    finalize_kernel<<<1, Bb, 0, stream>>>(red, out);
}